// Round 5
// baseline (8421.382 us; speedup 1.0000x reference)
//
#include <hip/hip_runtime.h>

// ---------------------------------------------------------------------------
// Persistent 2-layer LSTM, MI355X. Round 16 = STRUCTURAL: 512-thread WGs,
// 8 peers per role per group (was 16). r15 post-mortem: poll-frequency tuning
// was neutral -> chain is not poll-limited. Remaining levers: per-step
// straggler max over peers + per-agent LLC contention. This round halves the
// agent count: 8 L0-WGs + 8 L1-WGs per group, each 512 threads / 8 waves /
// 64 units. Per-wave compute is IDENTICAL (2 n-tiles, same W fragments/thread,
// 176 VGPR x 8 waves = exactly 1 WG/CU); blocking wait = max over 8 not 16;
// half the publishers/pollers per flag line; stage = 2 u64/thread; publish =
// 2 u64/lane (wave0). WS layout, depth-4/depth-2 plane rotation, merged L1
// wait+dual-stage (r13), EWMA predictive sleep + wave0-only polling (r15) all
// carried over verbatim. Grid: 128 WGs on 128 CUs.
// ---------------------------------------------------------------------------

#define T_STEPS 1024
#define WS_FLAG_OFF 0                     // 8 groups * 128 ints (512 B apart)
#define WS_H0_OFF  4096                   // [8 g][4 depth][8 wg][8 b][64 u] f16
#define WS_H1_OFF  (4096 + 8*4*8192)      // [8 g][2 depth][...]
#define WS_NEED    (WS_H1_OFF + 8*2*8192) // 397312 B (known-good size)

typedef _Float16 f16;
typedef _Float16 f16x8 __attribute__((ext_vector_type(8)));
typedef float    f32x4 __attribute__((ext_vector_type(4)));
typedef unsigned long long u64;

#define HP_STRIDE 520   // padded LDS plane row stride (f16)

__device__ __forceinline__ float sigm_(float x) {
    x = fminf(fmaxf(x, -30.f), 30.f);
    return 1.f / (1.f + __expf(-x));
}
__device__ __forceinline__ float tanh_(float x) {
    x = fminf(fmaxf(x, -15.f), 15.f);
    float e = __expf(-2.f * x);
    return (1.f - e) / (1.f + e);
}

// A-fragment for 16x16x32 f16 MFMA from a padded LDS plane.
// A[m=lane&15][k=(lane>>4)*8+j]; m = batch (0..7 valid, 8..15 -> zeros).
__device__ __forceinline__ f16x8 afrag_lds(const f16* __restrict__ hp, int kbase,
                                           int b, int q) {
    if (b < 8) {
        return *(const f16x8*)(hp + b * HP_STRIDE + kbase + q * 8);
    }
    f16x8 z = {(_Float16)0, (_Float16)0, (_Float16)0, (_Float16)0,
               (_Float16)0, (_Float16)0, (_Float16)0, (_Float16)0};
    return z;
}

__device__ __forceinline__ f16x8 pack8(const float* p) {
    float4 a = *(const float4*)p, b = *(const float4*)(p + 4);
    f16x8 f;
    f[0] = (f16)a.x; f[1] = (f16)a.y; f[2] = (f16)a.z; f[3] = (f16)a.w;
    f[4] = (f16)b.x; f[5] = (f16)b.y; f[6] = (f16)b.z; f[7] = (f16)b.w;
    return f;
}

// Wait until all 8 flag0 >= t0 AND all 8 flag1 >= t1.
// CALLED BY WAVE 0 ONLY. Lanes 0-7 load flag0, 16-23 load flag1, all other
// lanes contribute INT_MAX (no load). EWMA predictive coarse sleep
// (s_sleep(31) bursts) then fine-poll at 64cy quanta. Returns blocked
// duration in shader clocks (0 if fast path).
__device__ __forceinline__ long long wait_flags(const int* f0, int t0,
                                                const int* f1, int t1, int lane,
                                                long long predict_clk) {
    const int* p = (lane & 16) ? (f1 + (lane & 7)) : (f0 + (lane & 7));
    const int tgt = (lane & 16) ? t1 : t0;
    const bool act = ((lane & 15) < 8) && (lane < 32);
    int v = act ? __hip_atomic_load(p, __ATOMIC_RELAXED, __HIP_MEMORY_SCOPE_SYSTEM)
                : 0x7fffffff;
    if (__all(v >= tgt)) return 0;                 // fast path: no wait
    long long t0c = (long long)__builtin_amdgcn_s_memtime();
    int rep = (int)(predict_clk >> 12);            // ~half wait / ~2000cy burst
    if (rep > 8) rep = 8;
    for (int i = 0; i < rep; ++i) __builtin_amdgcn_s_sleep(31);
    int spins = 0;
    for (;;) {
        v = act ? __hip_atomic_load(p, __ATOMIC_RELAXED, __HIP_MEMORY_SCOPE_SYSTEM)
                : 0x7fffffff;
        if (__all(v >= tgt)) break;
        ++spins;
        if (spins < 32)       __builtin_amdgcn_s_sleep(1);
        else if (spins < 256) __builtin_amdgcn_s_sleep(4);
        else                  __builtin_amdgcn_s_sleep(16);
        if (spins > (1 << 20)) break;   // anti-hang safety valve
    }
    return (long long)__builtin_amdgcn_s_memtime() - t0c;
}

// EWMA update: decay toward the new sample (or toward 0 on fast path).
__device__ __forceinline__ long long ewma_upd(long long ew, long long d) {
    return ew - (ew >> 2) + (d >> 2);
}

// Stage one 8 KB h-plane ([8 wg][8 b][64 u] f16, WG-major global) into the
// padded LDS [batch][unit 0..511] plane. 512 threads x 2 u64.
// u64 i: wg=i>>7, b=(i>>4)&7, jw=i&15 (unit = jw*4).
__device__ __forceinline__ void stage_plane(const f16* __restrict__ gp,
                                            f16* __restrict__ dst, int tid) {
    const u64* g8 = (const u64*)gp;
    u64 v[2];
#pragma unroll
    for (int jj = 0; jj < 2; ++jj)
        v[jj] = __hip_atomic_load(g8 + jj * 512 + tid, __ATOMIC_RELAXED,
                                  __HIP_MEMORY_SCOPE_SYSTEM);
#pragma unroll
    for (int jj = 0; jj < 2; ++jj) {
        int i = jj * 512 + tid;
        int wg = i >> 7, b = (i >> 4) & 7, jw = i & 15;
        *(u64*)(dst + b * HP_STRIDE + wg * 64 + jw * 4) = v[jj];
    }
}

// Stage TWO 8 KB h-planes in one pass: all 4 global loads issued together
// (single LLC round-trip on the serial chain), then all 4 LDS writes.
__device__ __forceinline__ void stage_two(const f16* __restrict__ gpA,
                                          f16* __restrict__ dstA,
                                          const f16* __restrict__ gpB,
                                          f16* __restrict__ dstB, int tid) {
    const u64* ga = (const u64*)gpA;
    const u64* gb = (const u64*)gpB;
    u64 va[2], vb[2];
#pragma unroll
    for (int jj = 0; jj < 2; ++jj)
        va[jj] = __hip_atomic_load(ga + jj * 512 + tid, __ATOMIC_RELAXED,
                                   __HIP_MEMORY_SCOPE_SYSTEM);
#pragma unroll
    for (int jj = 0; jj < 2; ++jj)
        vb[jj] = __hip_atomic_load(gb + jj * 512 + tid, __ATOMIC_RELAXED,
                                   __HIP_MEMORY_SCOPE_SYSTEM);
#pragma unroll
    for (int jj = 0; jj < 2; ++jj) {
        int i = jj * 512 + tid;
        int wg = i >> 7, b = (i >> 4) & 7, jw = i & 15;
        *(u64*)(dstA + b * HP_STRIDE + wg * 64 + jw * 4) = va[jj];
        *(u64*)(dstB + b * HP_STRIDE + wg * 64 + jw * 4) = vb[jj];
    }
}

// x A-fragment for step t.
__device__ __forceinline__ f16x8 load_xfrag(const float* __restrict__ x,
                                            int gb8, int t, int ln, int q) {
    f16x8 f = {(_Float16)0, (_Float16)0, (_Float16)0, (_Float16)0,
               (_Float16)0, (_Float16)0, (_Float16)0, (_Float16)0};
    if (ln < 8 && t < T_STEPS) {
        const float* xp = x + ((size_t)(gb8 + ln) * 1024 + t) * 21;
#pragma unroll
        for (int j = 0; j < 8; ++j) {
            int kl = q * 8 + j;
            if (kl < 21) f[j] = (f16)xp[kl];
        }
    }
    return f;
}

// Zeros must be visible at the LLC -> system-scope stores.
__global__ void zero_ws_kernel(unsigned* __restrict__ p, int ndw) {
    int i = blockIdx.x * blockDim.x + threadIdx.x;
    int stride = gridDim.x * blockDim.x;
    for (; i < ndw; i += stride)
        __hip_atomic_store(p + i, 0u, __ATOMIC_RELAXED, __HIP_MEMORY_SCOPE_SYSTEM);
}

__global__ __launch_bounds__(512, 1)
void lstm_persist(const float* __restrict__ x,
                  const float* __restrict__ Wx0, const float* __restrict__ bx0,
                  const float* __restrict__ Wh0,
                  const float* __restrict__ Wx1, const float* __restrict__ bx1,
                  const float* __restrict__ Wh1,
                  const float* __restrict__ Wo,  const float* __restrict__ bo,
                  float* __restrict__ out, char* __restrict__ ws) {
    struct SM {
        float g[4][8][66];                       // gate tiles [gate][b][u0..63]+pad
        float c[8][64];                          // this WG's cell state
        float bias[4][64];                       // this WG's bias slice
        __align__(8)  f16 hout[8][64];           // activation -> packed store
        __align__(16) f16 planeA[8 * HP_STRIDE]; // h0 plane
        __align__(16) f16 planeB[8 * HP_STRIDE]; // h1 plane (L1 only)
        char  pad[56 * 1024];                    // force 1 WG/CU (total > 80 KB)
    };
    __shared__ SM sm;
    const int tid = threadIdx.x;
    if (tid == 0x00FFFFFFu) sm.pad[0] = 1;       // keep pad alive

    const int bid  = blockIdx.x;                 // 0..127
    const int g    = bid & 7;        // group (XCD-affine under round-robin)
    const int rk   = bid >> 3;       // 0..15 within group
    const int role = rk >> 3;        // 0: layer-0 WG, 1: layer-1 WG
    const int r    = rk & 7;         // rank within role (0..7)
    const int w    = tid >> 6;       // wave id 0..7: gate = w>>1, half = w&1
    const int lane = tid & 63;
    const int ln   = lane & 15;
    const int q    = lane >> 4;
    const int gb8  = g * 8;

    int* barb  = (int*)(ws + WS_FLAG_OFF) + g * 128;  // 512 B per group
    int* flag0 = barb;               // 8 per-L0-WG monotone step flags
    int* flag1 = barb + 64;          // 8 per-L1-WG flags (separate line)
    f16* H0g = (f16*)(ws + WS_H0_OFF) + g * 16384;  // 4 depth planes
    f16* H1g = (f16*)(ws + WS_H1_OFF) + g * 8192;   // 2 depth planes

    // ---- LDS init -------------------------------------------------------
    ((float*)sm.c)[tid] = 0.f;                   // 8*64 = 512 floats
    if (tid < 256) {
        int gate = tid >> 6, u = tid & 63;
        const float* bx = role ? bx1 : bx0;
        sm.bias[gate][u] = bx[(gate << 9) + (r << 6) + u];
    }

    // ---- persistent weight fragments in registers -----------------------
    // Wave w owns gate (w>>1), unit half (w&1): rows
    //   rw = (w>>1)*512 + r*64 + (w&1)*32 + tau*16 + ln, tau in {0,1}.
    // role 0 -> W[tau*17+kk] (K=544: Wh0|Wx0pad); role 1 -> W[tau*32+kk]
    // (K=1024: Wx1|Wh1). Same per-thread fragment count as the 256-thread
    // version (34 / 64).
    f16x8 W[64];
    if (role == 0) {
#pragma unroll
        for (int tau = 0; tau < 2; ++tau) {
            const int rw = ((w >> 1) << 9) + (r << 6) + ((w & 1) << 5) + tau * 16 + ln;
            const float* wh0r = Wh0 + (size_t)rw * 512;
#pragma unroll
            for (int kk = 0; kk < 16; ++kk)
                W[tau * 17 + kk] = pack8(wh0r + kk * 32 + q * 8);
            const float* wx0r = Wx0 + (size_t)rw * 21;
            f16x8 f = {(_Float16)0, (_Float16)0, (_Float16)0, (_Float16)0,
                       (_Float16)0, (_Float16)0, (_Float16)0, (_Float16)0};
#pragma unroll
            for (int j = 0; j < 8; ++j) {
                int kl = q * 8 + j;
                if (kl < 21) f[j] = (f16)wx0r[kl];
            }
            W[tau * 17 + 16] = f;
        }
    } else {
#pragma unroll
        for (int tau = 0; tau < 2; ++tau) {
            const int rw = ((w >> 1) << 9) + (r << 6) + ((w & 1) << 5) + tau * 16 + ln;
            const float* wx1r = Wx1 + (size_t)rw * 512;
            const float* wh1r = Wh1 + (size_t)rw * 512;
#pragma unroll
            for (int kk = 0; kk < 16; ++kk)
                W[tau * 32 + kk] = pack8(wx1r + kk * 32 + q * 8);
#pragma unroll
            for (int kk = 16; kk < 32; ++kk)
                W[tau * 32 + kk] = pack8(wh1r + (kk - 16) * 32 + q * 8);
        }
    }
    __syncthreads();

    const int gate = w >> 1;
    const int cb   = (w & 1) << 5;   // column base within WG's 64-unit slice

    if (role == 0) {
        // =================== layer-0 pipeline stage =======================
        // Writes h0(t) -> plane t&3. Waits flag1 >= t-3 so h0(t-4)'s plane is
        // consumed before overwrite; runs up to 3 steps ahead of L1.
        long long ew = 0;                          // EWMA of blocked wait (clk)
        for (int t = 0; t < T_STEPS; ++t) {
            const int wr = t & 3, rd = (t + 3) & 3;
            f16x8 xf = load_xfrag(x, gb8, t, ln, q);   // prefetch before wait
            if (tid < 64) {
                long long d = wait_flags(flag0, t, flag1, t - 3, lane, ew);
                ew = ewma_upd(ew, d);
            }
            __syncthreads();                           // release waves 1-7
            stage_plane(H0g + rd * 4096, sm.planeA, tid);
            __syncthreads();

            f32x4 a0 = {0, 0, 0, 0}, a1 = {0, 0, 0, 0};
#pragma unroll
            for (int kk = 0; kk < 16; ++kk) {
                f16x8 A = afrag_lds(sm.planeA, kk * 32, ln, q);
                a0 = __builtin_amdgcn_mfma_f32_16x16x32_f16(A, W[kk], a0, 0, 0, 0);
                a1 = __builtin_amdgcn_mfma_f32_16x16x32_f16(A, W[17 + kk], a1, 0, 0, 0);
            }
            a0 = __builtin_amdgcn_mfma_f32_16x16x32_f16(xf, W[16], a0, 0, 0, 0);
            a1 = __builtin_amdgcn_mfma_f32_16x16x32_f16(xf, W[33], a1, 0, 0, 0);
            if (q < 2) {
#pragma unroll
                for (int r4 = 0; r4 < 4; ++r4) {
                    sm.g[gate][q * 4 + r4][cb + ln] = a0[r4];
                    sm.g[gate][q * 4 + r4][cb + 16 + ln] = a1[r4];
                }
            }
            __syncthreads();
            {   // activation: 8 batches x 64 units = 512 threads
                int b = tid >> 6, u = tid & 63;
                float gi = sm.g[0][b][u] + sm.bias[0][u];
                float gf = sm.g[1][b][u] + sm.bias[1][u];
                float gg = sm.g[2][b][u] + sm.bias[2][u];
                float go = sm.g[3][b][u] + sm.bias[3][u];
                float iv = sigm_(gi), fv = sigm_(gf), gv = tanh_(gg), ov = sigm_(go);
                float c = sm.c[b][u];
                float cn = fv * c + iv * gv;
                sm.c[b][u] = cn;
                sm.hout[b][u] = (f16)(ov * tanh_(cn));
            }
            __syncthreads();
            if (tid < 64) {   // 1 KB contiguous WG slice, wave-0 only
                u64* dstp = (u64*)(H0g + wr * 4096) + (r << 7);
#pragma unroll
                for (int jj = 0; jj < 2; ++jj) {
                    int k = jj * 64 + lane;          // 0..127
                    int b = k >> 4, jw = k & 15;
                    u64 v = *(const u64*)&sm.hout[b][jw * 4];
                    __hip_atomic_store(dstp + k, v, __ATOMIC_RELAXED,
                                       __HIP_MEMORY_SCOPE_SYSTEM);
                }
                asm volatile("s_waitcnt vmcnt(0)" ::: "memory");
                if (tid == 0)
                    __hip_atomic_store(flag0 + r, t + 1, __ATOMIC_RELAXED,
                                       __HIP_MEMORY_SCOPE_SYSTEM);
            }
        }
    } else {
        // =================== layer-1 pipeline stage =======================
        // MERGED: one wait (flag0>=t+1 && flag1>=t), one dual-plane staging
        // pass, then all 64 MFMAs (r13 structure).
        long long ew = 0;                          // EWMA of blocked wait (clk)
        for (int t = 0; t < T_STEPS; ++t) {
            const int wr = t & 1, rd = wr ^ 1;

            if (tid < 64) {
                long long d = wait_flags(flag0, t + 1, flag1, t, lane, ew);
                ew = ewma_upd(ew, d);
            }
            __syncthreads();
            stage_two(H0g + (t & 3) * 4096, sm.planeA,   // h0(t)
                      H1g + rd * 4096,      sm.planeB,   // h1(t-1)
                      tid);
            __syncthreads();

            f32x4 a0 = {0, 0, 0, 0}, a1 = {0, 0, 0, 0};
#pragma unroll
            for (int kk = 0; kk < 16; ++kk) {
                f16x8 A = afrag_lds(sm.planeA, kk * 32, ln, q);
                a0 = __builtin_amdgcn_mfma_f32_16x16x32_f16(A, W[kk], a0, 0, 0, 0);
                a1 = __builtin_amdgcn_mfma_f32_16x16x32_f16(A, W[32 + kk], a1, 0, 0, 0);
            }
#pragma unroll
            for (int kk = 16; kk < 32; ++kk) {
                f16x8 A = afrag_lds(sm.planeB, (kk - 16) * 32, ln, q);
                a0 = __builtin_amdgcn_mfma_f32_16x16x32_f16(A, W[kk], a0, 0, 0, 0);
                a1 = __builtin_amdgcn_mfma_f32_16x16x32_f16(A, W[32 + kk], a1, 0, 0, 0);
            }
            if (q < 2) {
#pragma unroll
                for (int r4 = 0; r4 < 4; ++r4) {
                    sm.g[gate][q * 4 + r4][cb + ln] = a0[r4];
                    sm.g[gate][q * 4 + r4][cb + 16 + ln] = a1[r4];
                }
            }
            __syncthreads();
            {
                int b = tid >> 6, u = tid & 63;
                float gi = sm.g[0][b][u] + sm.bias[0][u];
                float gf = sm.g[1][b][u] + sm.bias[1][u];
                float gg = sm.g[2][b][u] + sm.bias[2][u];
                float go = sm.g[3][b][u] + sm.bias[3][u];
                float iv = sigm_(gi), fv = sigm_(gf), gv = tanh_(gg), ov = sigm_(go);
                float c = sm.c[b][u];
                float cn = fv * c + iv * gv;
                sm.c[b][u] = cn;
                sm.hout[b][u] = (f16)(ov * tanh_(cn));
            }
            __syncthreads();
            if (tid < 64) {
                u64* dstp = (u64*)(H1g + wr * 4096) + (r << 7);
#pragma unroll
                for (int jj = 0; jj < 2; ++jj) {
                    int k = jj * 64 + lane;
                    int b = k >> 4, jw = k & 15;
                    u64 v = *(const u64*)&sm.hout[b][jw * 4];
                    __hip_atomic_store(dstp + k, v, __ATOMIC_RELAXED,
                                       __HIP_MEMORY_SCOPE_SYSTEM);
                }
                asm volatile("s_waitcnt vmcnt(0)" ::: "memory");
                if (tid == 0)
                    __hip_atomic_store(flag1 + r, t + 1, __ATOMIC_RELAXED,
                                       __HIP_MEMORY_SCOPE_SYSTEM);
            }

            // ---- out-proj(t-1) AFTER publish, from LDS planeB (off the
            // inter-WG path). WG r handles batch b=r, all 20 outputs.
            // Safe: planeB's next overwrite is after the next wait's
            // __syncthreads, which orders it after these reads.
            if (t > 0) {
                int p = tid >> 4, kp = tid & 15;
                int valid = (p < 20);
                int b = r, o = valid ? p : 0;
                float a = 0.f;
                if (valid) {
                    const f16* hp = sm.planeB + b * HP_STRIDE + kp * 32;
                    const float* wo = Wo + (size_t)o * 512 + kp * 32;
#pragma unroll
                    for (int k = 0; k < 32; k += 8) {
                        f16x8 hv = *(const f16x8*)(hp + k);
                        float4 wa = *(const float4*)(wo + k);
                        float4 wb = *(const float4*)(wo + k + 4);
                        a += (float)hv[0] * wa.x + (float)hv[1] * wa.y +
                             (float)hv[2] * wa.z + (float)hv[3] * wa.w +
                             (float)hv[4] * wb.x + (float)hv[5] * wb.y +
                             (float)hv[6] * wb.z + (float)hv[7] * wb.w;
                    }
                }
                a += __shfl_down(a, 8, 16);
                a += __shfl_down(a, 4, 16);
                a += __shfl_down(a, 2, 16);
                a += __shfl_down(a, 1, 16);
                if (valid && kp == 0)
                    out[((size_t)(gb8 + b) * 1024 + (t - 1)) * 20 + o] =
                        sigm_(a + bo[o]);
            }
        }

        // ===== epilogue: out(T-1) from h1(T-1) =============================
        if (tid < 64) wait_flags(flag1, T_STEPS, flag1, T_STEPS, lane, 0);
        __syncthreads();
        stage_plane(H1g + ((T_STEPS - 1) & 1) * 4096, sm.planeB, tid);
        __syncthreads();
        {
            int p = tid >> 4, kp = tid & 15;
            int valid = (p < 20);
            int b = r, o = valid ? p : 0;
            float a = 0.f;
            if (valid) {
                const f16* hp = sm.planeB + b * HP_STRIDE + kp * 32;
                const float* wo = Wo + (size_t)o * 512 + kp * 32;
#pragma unroll
                for (int k = 0; k < 32; k += 8) {
                    f16x8 hv = *(const f16x8*)(hp + k);
                    float4 wa = *(const float4*)(wo + k);
                    float4 wb = *(const float4*)(wo + k + 4);
                    a += (float)hv[0] * wa.x + (float)hv[1] * wa.y +
                         (float)hv[2] * wa.z + (float)hv[3] * wa.w +
                         (float)hv[4] * wb.x + (float)hv[5] * wb.y +
                         (float)hv[6] * wb.z + (float)hv[7] * wb.w;
                }
            }
            a += __shfl_down(a, 8, 16);
            a += __shfl_down(a, 4, 16);
            a += __shfl_down(a, 2, 16);
            a += __shfl_down(a, 1, 16);
            if (valid && kp == 0)
                out[((size_t)(gb8 + b) * 1024 + (T_STEPS - 1)) * 20 + o] =
                    sigm_(a + bo[o]);
        }
    }
}

extern "C" void kernel_launch(void* const* d_in, const int* in_sizes, int n_in,
                              void* d_out, int out_size, void* d_ws, size_t ws_size,
                              hipStream_t stream) {
    const float* x   = (const float*)d_in[0];
    const float* Wx0 = (const float*)d_in[1];
    const float* bx0 = (const float*)d_in[2];
    const float* Wh0 = (const float*)d_in[3];
    const float* Wx1 = (const float*)d_in[4];
    const float* bx1 = (const float*)d_in[5];
    const float* Wh1 = (const float*)d_in[6];
    const float* Wo  = (const float*)d_in[7];
    const float* bo  = (const float*)d_in[8];
    float* out = (float*)d_out;
    char*  ws  = (char*)d_ws;

    if (ws_size < (size_t)WS_NEED) return;   // fail visibly (out stays poisoned)

    zero_ws_kernel<<<128, 256, 0, stream>>>((unsigned*)ws, WS_NEED / 4);
    lstm_persist<<<128, 512, 0, stream>>>(x, Wx0, bx0, Wh0, Wx1, bx1, Wh1,
                                          Wo, bo, out, ws);
}

// Round 6
// 4623.603 us; speedup vs baseline: 1.8214x; 1.8214x over previous
//
#include <hip/hip_runtime.h>

// ---------------------------------------------------------------------------
// Persistent 2-layer LSTM, MI355X. Round 17 = Round-15 base (4615 us, best)
// with ALL coherent ops switched SYSTEM -> AGENT (device) scope.
// r16 post-mortem: 512-thread WGs halved the per-wave register budget
// (2 waves/SIMD -> 256 regs/wave), W[64] spilled to scratch (VGPR 176->128,
// WRITE_SIZE +30MB), 2x regression. REVERTED to the 256-thread geometry,
// which is register-pinned: 4 waves x 1 wave/SIMD x <=512 regs holds W[] in
// the unified VGPR/AGPR file.
// This round's single change: __HIP_MEMORY_SCOPE_SYSTEM ->
// __HIP_MEMORY_SCOPE_AGENT on every flag/publish/stage/zero op. Cross-XCD
// coherence needs only device scope (resolved at the LLC); system scope is
// stronger than needed and may route through a slower coherence path. The
// L0 period is ~3 serial LLC RTs + compute; any per-RT saving multiplies by
// 3 x 1024 steps. Everything else r15 verbatim: 16 L0-WGs + 16 L1-WGs per
// group, weights in VGPRs, h0 depth-4 / h1 depth-2 planes, merged L1
// wait+dual-stage, EWMA predictive sleep, wave-0-only polling, 1 WG/CU pad.
// ---------------------------------------------------------------------------

#define T_STEPS 1024
#define WS_FLAG_OFF 0                     // 8 groups * 128 ints (512 B apart)
#define WS_H0_OFF  4096                   // [8 g][4 depth][16 wg][8 b][32 u] f16
#define WS_H1_OFF  (4096 + 8*4*8192)      // [8 g][2 depth][...]
#define WS_NEED    (WS_H1_OFF + 8*2*8192) // 397312 B (known-good size)

#define SCOPE __HIP_MEMORY_SCOPE_AGENT    // device scope: LLC-coherent, cross-XCD

typedef _Float16 f16;
typedef _Float16 f16x8 __attribute__((ext_vector_type(8)));
typedef float    f32x4 __attribute__((ext_vector_type(4)));
typedef unsigned long long u64;

#define HP_STRIDE 520   // padded LDS plane row stride (f16)

__device__ __forceinline__ float sigm_(float x) {
    x = fminf(fmaxf(x, -30.f), 30.f);
    return 1.f / (1.f + __expf(-x));
}
__device__ __forceinline__ float tanh_(float x) {
    x = fminf(fmaxf(x, -15.f), 15.f);
    float e = __expf(-2.f * x);
    return (1.f - e) / (1.f + e);
}

// A-fragment for 16x16x32 f16 MFMA from a padded LDS plane.
// A[m=lane&15][k=(lane>>4)*8+j]; m = batch (0..7 valid, 8..15 -> zeros).
__device__ __forceinline__ f16x8 afrag_lds(const f16* __restrict__ hp, int kbase,
                                           int b, int q) {
    if (b < 8) {
        return *(const f16x8*)(hp + b * HP_STRIDE + kbase + q * 8);
    }
    f16x8 z = {(_Float16)0, (_Float16)0, (_Float16)0, (_Float16)0,
               (_Float16)0, (_Float16)0, (_Float16)0, (_Float16)0};
    return z;
}

__device__ __forceinline__ f16x8 pack8(const float* p) {
    float4 a = *(const float4*)p, b = *(const float4*)(p + 4);
    f16x8 f;
    f[0] = (f16)a.x; f[1] = (f16)a.y; f[2] = (f16)a.z; f[3] = (f16)a.w;
    f[4] = (f16)b.x; f[5] = (f16)b.y; f[6] = (f16)b.z; f[7] = (f16)b.w;
    return f;
}

// Wait until all 16 flag0 >= t0 AND all 16 flag1 >= t1.
// CALLED BY WAVE 0 ONLY. Lanes 0-15 load flag0, 16-31 load flag1, lanes
// 32-63 contribute INT_MAX (no load -> half the flag-line requests).
// predict_clk: EWMA of this site's recent blocked durations (shader clocks);
// when the first check fails, coarse-sleep ~half of it (constant s_sleep(31)
// bursts, ~2000cy each), then fine-poll at 64cy quanta. Returns blocked
// duration (0 if fast path).
__device__ __forceinline__ long long wait_flags(const int* f0, int t0,
                                                const int* f1, int t1, int lane,
                                                long long predict_clk) {
    const int* p = (lane & 16) ? (f1 + (lane & 15)) : (f0 + (lane & 15));
    const int tgt = (lane & 16) ? t1 : t0;
    const bool act = (lane < 32);
    int v = act ? __hip_atomic_load(p, __ATOMIC_RELAXED, SCOPE)
                : 0x7fffffff;
    if (__all(v >= tgt)) return 0;                 // fast path: no wait
    long long t0c = (long long)__builtin_amdgcn_s_memtime();
    int rep = (int)(predict_clk >> 12);            // ~half wait / ~2000cy burst
    if (rep > 8) rep = 8;
    for (int i = 0; i < rep; ++i) __builtin_amdgcn_s_sleep(31);
    int spins = 0;
    for (;;) {
        v = act ? __hip_atomic_load(p, __ATOMIC_RELAXED, SCOPE)
                : 0x7fffffff;
        if (__all(v >= tgt)) break;
        ++spins;
        if (spins < 32)       __builtin_amdgcn_s_sleep(1);
        else if (spins < 256) __builtin_amdgcn_s_sleep(4);
        else                  __builtin_amdgcn_s_sleep(16);
        if (spins > (1 << 20)) break;   // anti-hang safety valve
    }
    return (long long)__builtin_amdgcn_s_memtime() - t0c;
}

// EWMA update: decay toward the new sample (or toward 0 on fast path).
__device__ __forceinline__ long long ewma_upd(long long ew, long long d) {
    return ew - (ew >> 2) + (d >> 2);
}

// Stage one 8 KB h-plane ([16 wg][8 b][32 u] f16, WG-major global) into the
// padded LDS [batch][unit 0..511] plane. u64 i: wg=i>>6, b=(i>>3)&7, j=i&7.
__device__ __forceinline__ void stage_plane(const f16* __restrict__ gp,
                                            f16* __restrict__ dst, int tid) {
    const u64* g8 = (const u64*)gp;
    u64 v[4];
#pragma unroll
    for (int jj = 0; jj < 4; ++jj)
        v[jj] = __hip_atomic_load(g8 + jj * 256 + tid, __ATOMIC_RELAXED, SCOPE);
#pragma unroll
    for (int jj = 0; jj < 4; ++jj) {
        int i = jj * 256 + tid;
        int wg = i >> 6, b = (i >> 3) & 7, j = i & 7;
        *(u64*)(dst + b * HP_STRIDE + wg * 32 + j * 4) = v[jj];
    }
}

// Stage TWO 8 KB h-planes in one pass: all 8 global loads issued together
// (single LLC round-trip on the serial chain), then all 8 LDS writes.
__device__ __forceinline__ void stage_two(const f16* __restrict__ gpA,
                                          f16* __restrict__ dstA,
                                          const f16* __restrict__ gpB,
                                          f16* __restrict__ dstB, int tid) {
    const u64* ga = (const u64*)gpA;
    const u64* gb = (const u64*)gpB;
    u64 va[4], vb[4];
#pragma unroll
    for (int jj = 0; jj < 4; ++jj)
        va[jj] = __hip_atomic_load(ga + jj * 256 + tid, __ATOMIC_RELAXED, SCOPE);
#pragma unroll
    for (int jj = 0; jj < 4; ++jj)
        vb[jj] = __hip_atomic_load(gb + jj * 256 + tid, __ATOMIC_RELAXED, SCOPE);
#pragma unroll
    for (int jj = 0; jj < 4; ++jj) {
        int i = jj * 256 + tid;
        int wg = i >> 6, b = (i >> 3) & 7, j = i & 7;
        *(u64*)(dstA + b * HP_STRIDE + wg * 32 + j * 4) = va[jj];
        *(u64*)(dstB + b * HP_STRIDE + wg * 32 + j * 4) = vb[jj];
    }
}

// x A-fragment for step t.
__device__ __forceinline__ f16x8 load_xfrag(const float* __restrict__ x,
                                            int gb8, int t, int ln, int q) {
    f16x8 f = {(_Float16)0, (_Float16)0, (_Float16)0, (_Float16)0,
               (_Float16)0, (_Float16)0, (_Float16)0, (_Float16)0};
    if (ln < 8 && t < T_STEPS) {
        const float* xp = x + ((size_t)(gb8 + ln) * 1024 + t) * 21;
#pragma unroll
        for (int j = 0; j < 8; ++j) {
            int kl = q * 8 + j;
            if (kl < 21) f[j] = (f16)xp[kl];
        }
    }
    return f;
}

// Zeros must be visible at the LLC -> device-scope stores.
__global__ void zero_ws_kernel(unsigned* __restrict__ p, int ndw) {
    int i = blockIdx.x * blockDim.x + threadIdx.x;
    int stride = gridDim.x * blockDim.x;
    for (; i < ndw; i += stride)
        __hip_atomic_store(p + i, 0u, __ATOMIC_RELAXED, SCOPE);
}

__global__ __launch_bounds__(256, 1)
void lstm_persist(const float* __restrict__ x,
                  const float* __restrict__ Wx0, const float* __restrict__ bx0,
                  const float* __restrict__ Wh0,
                  const float* __restrict__ Wx1, const float* __restrict__ bx1,
                  const float* __restrict__ Wh1,
                  const float* __restrict__ Wo,  const float* __restrict__ bo,
                  float* __restrict__ out, char* __restrict__ ws) {
    struct SM {
        float g[4][8][33];                       // gate tiles [gate][b][u0..31]+pad
        float c[8][32];                          // this WG's cell state
        float bias[4][32];                       // this WG's bias slice
        __align__(8)  f16 hout[8][32];           // activation -> packed store
        __align__(16) f16 planeA[8 * HP_STRIDE]; // h0 plane
        __align__(16) f16 planeB[8 * HP_STRIDE]; // h1 plane (L1 only)
        char  pad[60 * 1024];                    // force 1 WG/CU
    };
    __shared__ SM sm;
    const int tid = threadIdx.x;
    if (tid == 0x00FFFFFFu) sm.pad[0] = 1;       // keep pad alive

    const int bid  = blockIdx.x;
    const int g    = bid & 7;        // group (XCD-affine under round-robin)
    const int rk   = bid >> 3;       // 0..31 within group
    const int role = rk >> 4;        // 0: layer-0 WG, 1: layer-1 WG
    const int r    = rk & 15;        // rank within role
    const int w    = tid >> 6;       // wave id = gate type (i,f,g,o)
    const int lane = tid & 63;
    const int ln   = lane & 15;
    const int q    = lane >> 4;
    const int gb8  = g * 8;

    int* barb  = (int*)(ws + WS_FLAG_OFF) + g * 128;  // 512 B per group
    int* flag0 = barb;               // 16 per-L0-WG monotone step flags
    int* flag1 = barb + 64;          // 16 per-L1-WG flags (separate line)
    f16* H0g = (f16*)(ws + WS_H0_OFF) + g * 16384;  // 4 depth planes
    f16* H1g = (f16*)(ws + WS_H1_OFF) + g * 8192;   // 2 depth planes

    // ---- LDS init -------------------------------------------------------
    ((float*)sm.c)[tid] = 0.f;                   // 8*32 = 256 floats
    if (tid < 128) {
        int gate = tid >> 5, u = tid & 31;
        const float* bx = role ? bx1 : bx0;
        sm.bias[gate][u] = bx[(gate << 9) + (r << 5) + u];
    }

    // ---- persistent weight fragments in registers -----------------------
    // W[ ]: role 0 -> W[tau*17+kk] (K=544: Wh0|Wx0pad), tau in {0,1} n-tiles.
    //       role 1 -> W[tau*32+kk] (K=1024: Wx1|Wh1).
    f16x8 W[64];
    if (role == 0) {
#pragma unroll
        for (int tau = 0; tau < 2; ++tau) {
            const int rw = (w << 9) + (r << 5) + tau * 16 + ln;
            const float* wh0r = Wh0 + (size_t)rw * 512;
#pragma unroll
            for (int kk = 0; kk < 16; ++kk)
                W[tau * 17 + kk] = pack8(wh0r + kk * 32 + q * 8);
            const float* wx0r = Wx0 + (size_t)rw * 21;
            f16x8 f = {(_Float16)0, (_Float16)0, (_Float16)0, (_Float16)0,
                       (_Float16)0, (_Float16)0, (_Float16)0, (_Float16)0};
#pragma unroll
            for (int j = 0; j < 8; ++j) {
                int kl = q * 8 + j;
                if (kl < 21) f[j] = (f16)wx0r[kl];
            }
            W[tau * 17 + 16] = f;
        }
    } else {
#pragma unroll
        for (int tau = 0; tau < 2; ++tau) {
            const int rw = (w << 9) + (r << 5) + tau * 16 + ln;
            const float* wx1r = Wx1 + (size_t)rw * 512;
            const float* wh1r = Wh1 + (size_t)rw * 512;
#pragma unroll
            for (int kk = 0; kk < 16; ++kk)
                W[tau * 32 + kk] = pack8(wx1r + kk * 32 + q * 8);
#pragma unroll
            for (int kk = 16; kk < 32; ++kk)
                W[tau * 32 + kk] = pack8(wh1r + (kk - 16) * 32 + q * 8);
        }
    }
    __syncthreads();

    if (role == 0) {
        // =================== layer-0 pipeline stage =======================
        // Writes h0(t) -> plane t&3. Waits flag1 >= t-3 so h0(t-4)'s plane is
        // consumed before overwrite; runs up to 3 steps ahead of L1.
        long long ew = 0;                          // EWMA of blocked wait (clk)
        for (int t = 0; t < T_STEPS; ++t) {
            const int wr = t & 3, rd = (t + 3) & 3;
            f16x8 xf = load_xfrag(x, gb8, t, ln, q);   // prefetch before wait
            if (tid < 64) {
                long long d = wait_flags(flag0, t, flag1, t - 3, lane, ew);
                ew = ewma_upd(ew, d);
            }
            __syncthreads();                           // release waves 1-3
            stage_plane(H0g + rd * 4096, sm.planeA, tid);
            __syncthreads();

            f32x4 a0 = {0, 0, 0, 0}, a1 = {0, 0, 0, 0};
#pragma unroll
            for (int kk = 0; kk < 16; ++kk) {
                f16x8 A = afrag_lds(sm.planeA, kk * 32, ln, q);
                a0 = __builtin_amdgcn_mfma_f32_16x16x32_f16(A, W[kk], a0, 0, 0, 0);
                a1 = __builtin_amdgcn_mfma_f32_16x16x32_f16(A, W[17 + kk], a1, 0, 0, 0);
            }
            a0 = __builtin_amdgcn_mfma_f32_16x16x32_f16(xf, W[16], a0, 0, 0, 0);
            a1 = __builtin_amdgcn_mfma_f32_16x16x32_f16(xf, W[33], a1, 0, 0, 0);
            if (q < 2) {
#pragma unroll
                for (int r4 = 0; r4 < 4; ++r4) {
                    sm.g[w][q * 4 + r4][ln] = a0[r4];
                    sm.g[w][q * 4 + r4][16 + ln] = a1[r4];
                }
            }
            __syncthreads();
            {   // activation: 8 batches x 32 units = 256 threads
                int b = tid >> 5, u = tid & 31;
                float gi = sm.g[0][b][u] + sm.bias[0][u];
                float gf = sm.g[1][b][u] + sm.bias[1][u];
                float gg = sm.g[2][b][u] + sm.bias[2][u];
                float go = sm.g[3][b][u] + sm.bias[3][u];
                float iv = sigm_(gi), fv = sigm_(gf), gv = tanh_(gg), ov = sigm_(go);
                float c = sm.c[b][u];
                float cn = fv * c + iv * gv;
                sm.c[b][u] = cn;
                sm.hout[b][u] = (f16)(ov * tanh_(cn));
            }
            __syncthreads();
            if (tid < 64) {   // 512 B contiguous WG slice, wave-0 only
                int b = tid >> 3, j = tid & 7;
                u64 v = *(const u64*)&sm.hout[b][j * 4];
                __hip_atomic_store((u64*)(H0g + wr * 4096 + (r << 8) + (b << 5) + (j << 2)),
                                   v, __ATOMIC_RELAXED, SCOPE);
                asm volatile("s_waitcnt vmcnt(0)" ::: "memory");
                if (tid == 0)
                    __hip_atomic_store(flag0 + r, t + 1, __ATOMIC_RELAXED, SCOPE);
            }
        }
    } else {
        // =================== layer-1 pipeline stage =======================
        // MERGED: one wait (flag0>=t+1 && flag1>=t), one dual-plane staging
        // pass, then all 64 MFMAs (r13 structure).
        long long ew = 0;                          // EWMA of blocked wait (clk)
        for (int t = 0; t < T_STEPS; ++t) {
            const int wr = t & 1, rd = wr ^ 1;

            if (tid < 64) {
                long long d = wait_flags(flag0, t + 1, flag1, t, lane, ew);
                ew = ewma_upd(ew, d);
            }
            __syncthreads();
            stage_two(H0g + (t & 3) * 4096, sm.planeA,   // h0(t)
                      H1g + rd * 4096,      sm.planeB,   // h1(t-1)
                      tid);
            __syncthreads();

            f32x4 a0 = {0, 0, 0, 0}, a1 = {0, 0, 0, 0};
#pragma unroll
            for (int kk = 0; kk < 16; ++kk) {
                f16x8 A = afrag_lds(sm.planeA, kk * 32, ln, q);
                a0 = __builtin_amdgcn_mfma_f32_16x16x32_f16(A, W[kk], a0, 0, 0, 0);
                a1 = __builtin_amdgcn_mfma_f32_16x16x32_f16(A, W[32 + kk], a1, 0, 0, 0);
            }
#pragma unroll
            for (int kk = 16; kk < 32; ++kk) {
                f16x8 A = afrag_lds(sm.planeB, (kk - 16) * 32, ln, q);
                a0 = __builtin_amdgcn_mfma_f32_16x16x32_f16(A, W[kk], a0, 0, 0, 0);
                a1 = __builtin_amdgcn_mfma_f32_16x16x32_f16(A, W[32 + kk], a1, 0, 0, 0);
            }
            if (q < 2) {
#pragma unroll
                for (int r4 = 0; r4 < 4; ++r4) {
                    sm.g[w][q * 4 + r4][ln] = a0[r4];
                    sm.g[w][q * 4 + r4][16 + ln] = a1[r4];
                }
            }
            __syncthreads();
            {
                int b = tid >> 5, u = tid & 31;
                float gi = sm.g[0][b][u] + sm.bias[0][u];
                float gf = sm.g[1][b][u] + sm.bias[1][u];
                float gg = sm.g[2][b][u] + sm.bias[2][u];
                float go = sm.g[3][b][u] + sm.bias[3][u];
                float iv = sigm_(gi), fv = sigm_(gf), gv = tanh_(gg), ov = sigm_(go);
                float c = sm.c[b][u];
                float cn = fv * c + iv * gv;
                sm.c[b][u] = cn;
                sm.hout[b][u] = (f16)(ov * tanh_(cn));
            }
            __syncthreads();
            if (tid < 64) {
                int b = tid >> 3, j = tid & 7;
                u64 v = *(const u64*)&sm.hout[b][j * 4];
                __hip_atomic_store((u64*)(H1g + wr * 4096 + (r << 8) + (b << 5) + (j << 2)),
                                   v, __ATOMIC_RELAXED, SCOPE);
                asm volatile("s_waitcnt vmcnt(0)" ::: "memory");
                if (tid == 0)
                    __hip_atomic_store(flag1 + r, t + 1, __ATOMIC_RELAXED, SCOPE);
            }

            // ---- out-proj(t-1) AFTER publish, from LDS planeB (off the
            // inter-WG path; also hides peers' flag1 crossing for step t+1).
            // Safe: planeB's next overwrite is after the next wait's
            // __syncthreads, which orders it after these reads.
            if (t > 0) {
                int p = tid >> 4, kp = tid & 15;
                int valid = (p < 10);
                int idx = r * 10 + p;
                int b = valid ? idx / 20 : 0, o = valid ? idx % 20 : 0;
                float a = 0.f;
                if (valid) {
                    const f16* hp = sm.planeB + b * HP_STRIDE + kp * 32;
                    const float* wo = Wo + (size_t)o * 512 + kp * 32;
#pragma unroll
                    for (int k = 0; k < 32; k += 8) {
                        f16x8 hv = *(const f16x8*)(hp + k);
                        float4 wa = *(const float4*)(wo + k);
                        float4 wb = *(const float4*)(wo + k + 4);
                        a += (float)hv[0] * wa.x + (float)hv[1] * wa.y +
                             (float)hv[2] * wa.z + (float)hv[3] * wa.w +
                             (float)hv[4] * wb.x + (float)hv[5] * wb.y +
                             (float)hv[6] * wb.z + (float)hv[7] * wb.w;
                    }
                }
                a += __shfl_down(a, 8, 16);
                a += __shfl_down(a, 4, 16);
                a += __shfl_down(a, 2, 16);
                a += __shfl_down(a, 1, 16);
                if (valid && kp == 0)
                    out[((size_t)(gb8 + b) * 1024 + (t - 1)) * 20 + o] =
                        sigm_(a + bo[o]);
            }
        }

        // ===== epilogue: out(T-1) from h1(T-1) =============================
        if (tid < 64) wait_flags(flag1, T_STEPS, flag1, T_STEPS, lane, 0);
        __syncthreads();
        stage_plane(H1g + ((T_STEPS - 1) & 1) * 4096, sm.planeB, tid);
        __syncthreads();
        {
            int p = tid >> 4, kp = tid & 15;
            int valid = (p < 10);
            int idx = r * 10 + p;
            int b = valid ? idx / 20 : 0, o = valid ? idx % 20 : 0;
            float a = 0.f;
            if (valid) {
                const f16* hp = sm.planeB + b * HP_STRIDE + kp * 32;
                const float* wo = Wo + (size_t)o * 512 + kp * 32;
#pragma unroll
                for (int k = 0; k < 32; k += 8) {
                    f16x8 hv = *(const f16x8*)(hp + k);
                    float4 wa = *(const float4*)(wo + k);
                    float4 wb = *(const float4*)(wo + k + 4);
                    a += (float)hv[0] * wa.x + (float)hv[1] * wa.y +
                         (float)hv[2] * wa.z + (float)hv[3] * wa.w +
                         (float)hv[4] * wb.x + (float)hv[5] * wb.y +
                         (float)hv[6] * wb.z + (float)hv[7] * wb.w;
                }
            }
            a += __shfl_down(a, 8, 16);
            a += __shfl_down(a, 4, 16);
            a += __shfl_down(a, 2, 16);
            a += __shfl_down(a, 1, 16);
            if (valid && kp == 0)
                out[((size_t)(gb8 + b) * 1024 + (T_STEPS - 1)) * 20 + o] =
                    sigm_(a + bo[o]);
        }
    }
}

extern "C" void kernel_launch(void* const* d_in, const int* in_sizes, int n_in,
                              void* d_out, int out_size, void* d_ws, size_t ws_size,
                              hipStream_t stream) {
    const float* x   = (const float*)d_in[0];
    const float* Wx0 = (const float*)d_in[1];
    const float* bx0 = (const float*)d_in[2];
    const float* Wh0 = (const float*)d_in[3];
    const float* Wx1 = (const float*)d_in[4];
    const float* bx1 = (const float*)d_in[5];
    const float* Wh1 = (const float*)d_in[6];
    const float* Wo  = (const float*)d_in[7];
    const float* bo  = (const float*)d_in[8];
    float* out = (float*)d_out;
    char*  ws  = (char*)d_ws;

    if (ws_size < (size_t)WS_NEED) return;   // fail visibly (out stays poisoned)

    zero_ws_kernel<<<128, 256, 0, stream>>>((unsigned*)ws, WS_NEED / 4);
    lstm_persist<<<256, 256, 0, stream>>>(x, Wx0, bx0, Wh0, Wx1, bx1, Wh1,
                                          Wo, bo, out, ws);
}

// Round 7
// 3712.919 us; speedup vs baseline: 2.2681x; 1.2453x over previous
//
#include <hip/hip_runtime.h>

// ---------------------------------------------------------------------------
// Persistent 2-layer LSTM, MI355X. Round 18 = Round-17 base (4623 us) +
// PRIVATE PUBLISHER FLAG SLOTS + BRANCHLESS A-FRAGMENTS.
// Ledger: poll freq (r15 neutral), agent count (r16 spill regression), scope
// (r17 neutral), L1 RT count (r12/r13 real 1:1). Remaining unexplained
// ~1.9us/step. This round attacks two untouched serial-chain terms:
// (1) All 16 publishers per role shared ONE 64B flag line -> 16-writer
//     migratory-line serialization every step; the LAST flag (the one the
//     __all vote waits on) lands late. Fix: private 16B slot per publisher
//     (32 x 16B = 512B = the existing per-group flag region, zero layout
//     risk). Same-line writers 16 -> 4.
// (2) afrag_lds's b<8 branch + zero-vector build ran per MFMA operand
//     (34-64x/step). MFMA result rows 8-15 are discarded (q<2 store guard),
//     so lanes 8-15 just re-read rows 0-7 (b&7): branchless, finite data.
// Everything else r17 verbatim: 16+16 WGs/group, weights in VGPRs, depth-4/
// depth-2 planes, merged L1 wait+dual-stage, EWMA predictive sleep,
// wave-0-only polling, agent-scope LLC ops, 1 WG/CU pad.
// ---------------------------------------------------------------------------

#define T_STEPS 1024
#define WS_FLAG_OFF 0                     // 8 groups * 512 B: 32 pubs x 16 B each
#define WS_H0_OFF  4096                   // [8 g][4 depth][16 wg][8 b][32 u] f16
#define WS_H1_OFF  (4096 + 8*4*8192)      // [8 g][2 depth][...]
#define WS_NEED    (WS_H1_OFF + 8*2*8192) // 397312 B (known-good size)

#define SCOPE __HIP_MEMORY_SCOPE_AGENT    // device scope: LLC-coherent, cross-XCD

typedef _Float16 f16;
typedef _Float16 f16x8 __attribute__((ext_vector_type(8)));
typedef float    f32x4 __attribute__((ext_vector_type(4)));
typedef unsigned long long u64;

#define HP_STRIDE 520   // padded LDS plane row stride (f16)

__device__ __forceinline__ float sigm_(float x) {
    x = fminf(fmaxf(x, -30.f), 30.f);
    return 1.f / (1.f + __expf(-x));
}
__device__ __forceinline__ float tanh_(float x) {
    x = fminf(fmaxf(x, -15.f), 15.f);
    float e = __expf(-2.f * x);
    return (1.f - e) / (1.f + e);
}

// A-fragment for 16x16x32 f16 MFMA from a padded LDS plane — BRANCHLESS.
// A[m=lane&15][k=(lane>>4)*8+j]; m = batch. Lanes 8-15 re-read rows 0-7
// ((b&7)): their product rows 8-15 of D are discarded by the q<2 store
// guard, and the data is finite (no NaN/Inf), so duplication is safe.
__device__ __forceinline__ f16x8 afrag_lds(const f16* __restrict__ hp, int kbase,
                                           int b, int q) {
    return *(const f16x8*)(hp + (b & 7) * HP_STRIDE + kbase + q * 8);
}

__device__ __forceinline__ f16x8 pack8(const float* p) {
    float4 a = *(const float4*)p, b = *(const float4*)(p + 4);
    f16x8 f;
    f[0] = (f16)a.x; f[1] = (f16)a.y; f[2] = (f16)a.z; f[3] = (f16)a.w;
    f[4] = (f16)b.x; f[5] = (f16)b.y; f[6] = (f16)b.z; f[7] = (f16)b.w;
    return f;
}

// Wait until all 16 flag0 >= t0 AND all 16 flag1 >= t1.
// Flags live in PRIVATE 16B slots: rank r's flag at base + r*4 (ints).
// CALLED BY WAVE 0 ONLY. Lanes 0-15 load flag0 slots, 16-31 flag1 slots,
// lanes 32-63 contribute INT_MAX (no load). EWMA predictive coarse sleep
// (constant s_sleep(31) bursts) then fine-poll at 64cy quanta. Returns
// blocked duration (0 if fast path).
__device__ __forceinline__ long long wait_flags(const int* f0, int t0,
                                                const int* f1, int t1, int lane,
                                                long long predict_clk) {
    const int* p = (lane & 16) ? (f1 + (lane & 15) * 4) : (f0 + (lane & 15) * 4);
    const int tgt = (lane & 16) ? t1 : t0;
    const bool act = (lane < 32);
    int v = act ? __hip_atomic_load(p, __ATOMIC_RELAXED, SCOPE)
                : 0x7fffffff;
    if (__all(v >= tgt)) return 0;                 // fast path: no wait
    long long t0c = (long long)__builtin_amdgcn_s_memtime();
    int rep = (int)(predict_clk >> 12);            // ~half wait / ~2000cy burst
    if (rep > 8) rep = 8;
    for (int i = 0; i < rep; ++i) __builtin_amdgcn_s_sleep(31);
    int spins = 0;
    for (;;) {
        v = act ? __hip_atomic_load(p, __ATOMIC_RELAXED, SCOPE)
                : 0x7fffffff;
        if (__all(v >= tgt)) break;
        ++spins;
        if (spins < 32)       __builtin_amdgcn_s_sleep(1);
        else if (spins < 256) __builtin_amdgcn_s_sleep(4);
        else                  __builtin_amdgcn_s_sleep(16);
        if (spins > (1 << 20)) break;   // anti-hang safety valve
    }
    return (long long)__builtin_amdgcn_s_memtime() - t0c;
}

// EWMA update: decay toward the new sample (or toward 0 on fast path).
__device__ __forceinline__ long long ewma_upd(long long ew, long long d) {
    return ew - (ew >> 2) + (d >> 2);
}

// Stage one 8 KB h-plane ([16 wg][8 b][32 u] f16, WG-major global) into the
// padded LDS [batch][unit 0..511] plane. u64 i: wg=i>>6, b=(i>>3)&7, j=i&7.
__device__ __forceinline__ void stage_plane(const f16* __restrict__ gp,
                                            f16* __restrict__ dst, int tid) {
    const u64* g8 = (const u64*)gp;
    u64 v[4];
#pragma unroll
    for (int jj = 0; jj < 4; ++jj)
        v[jj] = __hip_atomic_load(g8 + jj * 256 + tid, __ATOMIC_RELAXED, SCOPE);
#pragma unroll
    for (int jj = 0; jj < 4; ++jj) {
        int i = jj * 256 + tid;
        int wg = i >> 6, b = (i >> 3) & 7, j = i & 7;
        *(u64*)(dst + b * HP_STRIDE + wg * 32 + j * 4) = v[jj];
    }
}

// Stage TWO 8 KB h-planes in one pass: all 8 global loads issued together
// (single LLC round-trip on the serial chain), then all 8 LDS writes.
__device__ __forceinline__ void stage_two(const f16* __restrict__ gpA,
                                          f16* __restrict__ dstA,
                                          const f16* __restrict__ gpB,
                                          f16* __restrict__ dstB, int tid) {
    const u64* ga = (const u64*)gpA;
    const u64* gb = (const u64*)gpB;
    u64 va[4], vb[4];
#pragma unroll
    for (int jj = 0; jj < 4; ++jj)
        va[jj] = __hip_atomic_load(ga + jj * 256 + tid, __ATOMIC_RELAXED, SCOPE);
#pragma unroll
    for (int jj = 0; jj < 4; ++jj)
        vb[jj] = __hip_atomic_load(gb + jj * 256 + tid, __ATOMIC_RELAXED, SCOPE);
#pragma unroll
    for (int jj = 0; jj < 4; ++jj) {
        int i = jj * 256 + tid;
        int wg = i >> 6, b = (i >> 3) & 7, j = i & 7;
        *(u64*)(dstA + b * HP_STRIDE + wg * 32 + j * 4) = va[jj];
        *(u64*)(dstB + b * HP_STRIDE + wg * 32 + j * 4) = vb[jj];
    }
}

// x A-fragment for step t.
__device__ __forceinline__ f16x8 load_xfrag(const float* __restrict__ x,
                                            int gb8, int t, int ln, int q) {
    f16x8 f = {(_Float16)0, (_Float16)0, (_Float16)0, (_Float16)0,
               (_Float16)0, (_Float16)0, (_Float16)0, (_Float16)0};
    if (ln < 8 && t < T_STEPS) {
        const float* xp = x + ((size_t)(gb8 + ln) * 1024 + t) * 21;
#pragma unroll
        for (int j = 0; j < 8; ++j) {
            int kl = q * 8 + j;
            if (kl < 21) f[j] = (f16)xp[kl];
        }
    }
    return f;
}

// Zeros must be visible at the LLC -> device-scope stores.
__global__ void zero_ws_kernel(unsigned* __restrict__ p, int ndw) {
    int i = blockIdx.x * blockDim.x + threadIdx.x;
    int stride = gridDim.x * blockDim.x;
    for (; i < ndw; i += stride)
        __hip_atomic_store(p + i, 0u, __ATOMIC_RELAXED, SCOPE);
}

__global__ __launch_bounds__(256, 1)
void lstm_persist(const float* __restrict__ x,
                  const float* __restrict__ Wx0, const float* __restrict__ bx0,
                  const float* __restrict__ Wh0,
                  const float* __restrict__ Wx1, const float* __restrict__ bx1,
                  const float* __restrict__ Wh1,
                  const float* __restrict__ Wo,  const float* __restrict__ bo,
                  float* __restrict__ out, char* __restrict__ ws) {
    struct SM {
        float g[4][8][33];                       // gate tiles [gate][b][u0..31]+pad
        float c[8][32];                          // this WG's cell state
        float bias[4][32];                       // this WG's bias slice
        __align__(8)  f16 hout[8][32];           // activation -> packed store
        __align__(16) f16 planeA[8 * HP_STRIDE]; // h0 plane
        __align__(16) f16 planeB[8 * HP_STRIDE]; // h1 plane (L1 only)
        char  pad[60 * 1024];                    // force 1 WG/CU
    };
    __shared__ SM sm;
    const int tid = threadIdx.x;
    if (tid == 0x00FFFFFFu) sm.pad[0] = 1;       // keep pad alive

    const int bid  = blockIdx.x;
    const int g    = bid & 7;        // group (XCD-affine under round-robin)
    const int rk   = bid >> 3;       // 0..31 within group
    const int role = rk >> 4;        // 0: layer-0 WG, 1: layer-1 WG
    const int r    = rk & 15;        // rank within role
    const int w    = tid >> 6;       // wave id = gate type (i,f,g,o)
    const int lane = tid & 63;
    const int ln   = lane & 15;
    const int q    = lane >> 4;
    const int gb8  = g * 8;

    // Flags: per-group 512 B; publisher (role,r) owns a PRIVATE 16 B slot.
    // flag0 rank r at barb + r*4 ints; flag1 rank r at barb + 64 + r*4.
    int* barb  = (int*)(ws + WS_FLAG_OFF) + g * 128;
    int* flag0 = barb;
    int* flag1 = barb + 64;
    f16* H0g = (f16*)(ws + WS_H0_OFF) + g * 16384;  // 4 depth planes
    f16* H1g = (f16*)(ws + WS_H1_OFF) + g * 8192;   // 2 depth planes

    // ---- LDS init -------------------------------------------------------
    ((float*)sm.c)[tid] = 0.f;                   // 8*32 = 256 floats
    if (tid < 128) {
        int gate = tid >> 5, u = tid & 31;
        const float* bx = role ? bx1 : bx0;
        sm.bias[gate][u] = bx[(gate << 9) + (r << 5) + u];
    }

    // ---- persistent weight fragments in registers -----------------------
    // W[ ]: role 0 -> W[tau*17+kk] (K=544: Wh0|Wx0pad), tau in {0,1} n-tiles.
    //       role 1 -> W[tau*32+kk] (K=1024: Wx1|Wh1).
    f16x8 W[64];
    if (role == 0) {
#pragma unroll
        for (int tau = 0; tau < 2; ++tau) {
            const int rw = (w << 9) + (r << 5) + tau * 16 + ln;
            const float* wh0r = Wh0 + (size_t)rw * 512;
#pragma unroll
            for (int kk = 0; kk < 16; ++kk)
                W[tau * 17 + kk] = pack8(wh0r + kk * 32 + q * 8);
            const float* wx0r = Wx0 + (size_t)rw * 21;
            f16x8 f = {(_Float16)0, (_Float16)0, (_Float16)0, (_Float16)0,
                       (_Float16)0, (_Float16)0, (_Float16)0, (_Float16)0};
#pragma unroll
            for (int j = 0; j < 8; ++j) {
                int kl = q * 8 + j;
                if (kl < 21) f[j] = (f16)wx0r[kl];
            }
            W[tau * 17 + 16] = f;
        }
    } else {
#pragma unroll
        for (int tau = 0; tau < 2; ++tau) {
            const int rw = (w << 9) + (r << 5) + tau * 16 + ln;
            const float* wx1r = Wx1 + (size_t)rw * 512;
            const float* wh1r = Wh1 + (size_t)rw * 512;
#pragma unroll
            for (int kk = 0; kk < 16; ++kk)
                W[tau * 32 + kk] = pack8(wx1r + kk * 32 + q * 8);
#pragma unroll
            for (int kk = 16; kk < 32; ++kk)
                W[tau * 32 + kk] = pack8(wh1r + (kk - 16) * 32 + q * 8);
        }
    }
    __syncthreads();

    if (role == 0) {
        // =================== layer-0 pipeline stage =======================
        // Writes h0(t) -> plane t&3. Waits flag1 >= t-3 so h0(t-4)'s plane is
        // consumed before overwrite; runs up to 3 steps ahead of L1.
        long long ew = 0;                          // EWMA of blocked wait (clk)
        for (int t = 0; t < T_STEPS; ++t) {
            const int wr = t & 3, rd = (t + 3) & 3;
            f16x8 xf = load_xfrag(x, gb8, t, ln, q);   // prefetch before wait
            if (tid < 64) {
                long long d = wait_flags(flag0, t, flag1, t - 3, lane, ew);
                ew = ewma_upd(ew, d);
            }
            __syncthreads();                           // release waves 1-3
            stage_plane(H0g + rd * 4096, sm.planeA, tid);
            __syncthreads();

            f32x4 a0 = {0, 0, 0, 0}, a1 = {0, 0, 0, 0};
#pragma unroll
            for (int kk = 0; kk < 16; ++kk) {
                f16x8 A = afrag_lds(sm.planeA, kk * 32, ln, q);
                a0 = __builtin_amdgcn_mfma_f32_16x16x32_f16(A, W[kk], a0, 0, 0, 0);
                a1 = __builtin_amdgcn_mfma_f32_16x16x32_f16(A, W[17 + kk], a1, 0, 0, 0);
            }
            a0 = __builtin_amdgcn_mfma_f32_16x16x32_f16(xf, W[16], a0, 0, 0, 0);
            a1 = __builtin_amdgcn_mfma_f32_16x16x32_f16(xf, W[33], a1, 0, 0, 0);
            if (q < 2) {
#pragma unroll
                for (int r4 = 0; r4 < 4; ++r4) {
                    sm.g[w][q * 4 + r4][ln] = a0[r4];
                    sm.g[w][q * 4 + r4][16 + ln] = a1[r4];
                }
            }
            __syncthreads();
            {   // activation: 8 batches x 32 units = 256 threads
                int b = tid >> 5, u = tid & 31;
                float gi = sm.g[0][b][u] + sm.bias[0][u];
                float gf = sm.g[1][b][u] + sm.bias[1][u];
                float gg = sm.g[2][b][u] + sm.bias[2][u];
                float go = sm.g[3][b][u] + sm.bias[3][u];
                float iv = sigm_(gi), fv = sigm_(gf), gv = tanh_(gg), ov = sigm_(go);
                float c = sm.c[b][u];
                float cn = fv * c + iv * gv;
                sm.c[b][u] = cn;
                sm.hout[b][u] = (f16)(ov * tanh_(cn));
            }
            __syncthreads();
            if (tid < 64) {   // 512 B contiguous WG slice, wave-0 only
                int b = tid >> 3, j = tid & 7;
                u64 v = *(const u64*)&sm.hout[b][j * 4];
                __hip_atomic_store((u64*)(H0g + wr * 4096 + (r << 8) + (b << 5) + (j << 2)),
                                   v, __ATOMIC_RELAXED, SCOPE);
                asm volatile("s_waitcnt vmcnt(0)" ::: "memory");
                if (tid == 0)
                    __hip_atomic_store(flag0 + r * 4, t + 1, __ATOMIC_RELAXED, SCOPE);
            }
        }
    } else {
        // =================== layer-1 pipeline stage =======================
        // MERGED: one wait (flag0>=t+1 && flag1>=t), one dual-plane staging
        // pass, then all 64 MFMAs (r13 structure).
        long long ew = 0;                          // EWMA of blocked wait (clk)
        for (int t = 0; t < T_STEPS; ++t) {
            const int wr = t & 1, rd = wr ^ 1;

            if (tid < 64) {
                long long d = wait_flags(flag0, t + 1, flag1, t, lane, ew);
                ew = ewma_upd(ew, d);
            }
            __syncthreads();
            stage_two(H0g + (t & 3) * 4096, sm.planeA,   // h0(t)
                      H1g + rd * 4096,      sm.planeB,   // h1(t-1)
                      tid);
            __syncthreads();

            f32x4 a0 = {0, 0, 0, 0}, a1 = {0, 0, 0, 0};
#pragma unroll
            for (int kk = 0; kk < 16; ++kk) {
                f16x8 A = afrag_lds(sm.planeA, kk * 32, ln, q);
                a0 = __builtin_amdgcn_mfma_f32_16x16x32_f16(A, W[kk], a0, 0, 0, 0);
                a1 = __builtin_amdgcn_mfma_f32_16x16x32_f16(A, W[32 + kk], a1, 0, 0, 0);
            }
#pragma unroll
            for (int kk = 16; kk < 32; ++kk) {
                f16x8 A = afrag_lds(sm.planeB, (kk - 16) * 32, ln, q);
                a0 = __builtin_amdgcn_mfma_f32_16x16x32_f16(A, W[kk], a0, 0, 0, 0);
                a1 = __builtin_amdgcn_mfma_f32_16x16x32_f16(A, W[32 + kk], a1, 0, 0, 0);
            }
            if (q < 2) {
#pragma unroll
                for (int r4 = 0; r4 < 4; ++r4) {
                    sm.g[w][q * 4 + r4][ln] = a0[r4];
                    sm.g[w][q * 4 + r4][16 + ln] = a1[r4];
                }
            }
            __syncthreads();
            {
                int b = tid >> 5, u = tid & 31;
                float gi = sm.g[0][b][u] + sm.bias[0][u];
                float gf = sm.g[1][b][u] + sm.bias[1][u];
                float gg = sm.g[2][b][u] + sm.bias[2][u];
                float go = sm.g[3][b][u] + sm.bias[3][u];
                float iv = sigm_(gi), fv = sigm_(gf), gv = tanh_(gg), ov = sigm_(go);
                float c = sm.c[b][u];
                float cn = fv * c + iv * gv;
                sm.c[b][u] = cn;
                sm.hout[b][u] = (f16)(ov * tanh_(cn));
            }
            __syncthreads();
            if (tid < 64) {
                int b = tid >> 3, j = tid & 7;
                u64 v = *(const u64*)&sm.hout[b][j * 4];
                __hip_atomic_store((u64*)(H1g + wr * 4096 + (r << 8) + (b << 5) + (j << 2)),
                                   v, __ATOMIC_RELAXED, SCOPE);
                asm volatile("s_waitcnt vmcnt(0)" ::: "memory");
                if (tid == 0)
                    __hip_atomic_store(flag1 + r * 4, t + 1, __ATOMIC_RELAXED, SCOPE);
            }

            // ---- out-proj(t-1) AFTER publish, from LDS planeB (off the
            // inter-WG path; also hides peers' flag1 crossing for step t+1).
            // Safe: planeB's next overwrite is after the next wait's
            // __syncthreads, which orders it after these reads.
            if (t > 0) {
                int p = tid >> 4, kp = tid & 15;
                int valid = (p < 10);
                int idx = r * 10 + p;
                int b = valid ? idx / 20 : 0, o = valid ? idx % 20 : 0;
                float a = 0.f;
                if (valid) {
                    const f16* hp = sm.planeB + b * HP_STRIDE + kp * 32;
                    const float* wo = Wo + (size_t)o * 512 + kp * 32;
#pragma unroll
                    for (int k = 0; k < 32; k += 8) {
                        f16x8 hv = *(const f16x8*)(hp + k);
                        float4 wa = *(const float4*)(wo + k);
                        float4 wb = *(const float4*)(wo + k + 4);
                        a += (float)hv[0] * wa.x + (float)hv[1] * wa.y +
                             (float)hv[2] * wa.z + (float)hv[3] * wa.w +
                             (float)hv[4] * wb.x + (float)hv[5] * wb.y +
                             (float)hv[6] * wb.z + (float)hv[7] * wb.w;
                    }
                }
                a += __shfl_down(a, 8, 16);
                a += __shfl_down(a, 4, 16);
                a += __shfl_down(a, 2, 16);
                a += __shfl_down(a, 1, 16);
                if (valid && kp == 0)
                    out[((size_t)(gb8 + b) * 1024 + (t - 1)) * 20 + o] =
                        sigm_(a + bo[o]);
            }
        }

        // ===== epilogue: out(T-1) from h1(T-1) =============================
        if (tid < 64) wait_flags(flag1, T_STEPS, flag1, T_STEPS, lane, 0);
        __syncthreads();
        stage_plane(H1g + ((T_STEPS - 1) & 1) * 4096, sm.planeB, tid);
        __syncthreads();
        {
            int p = tid >> 4, kp = tid & 15;
            int valid = (p < 10);
            int idx = r * 10 + p;
            int b = valid ? idx / 20 : 0, o = valid ? idx % 20 : 0;
            float a = 0.f;
            if (valid) {
                const f16* hp = sm.planeB + b * HP_STRIDE + kp * 32;
                const float* wo = Wo + (size_t)o * 512 + kp * 32;
#pragma unroll
                for (int k = 0; k < 32; k += 8) {
                    f16x8 hv = *(const f16x8*)(hp + k);
                    float4 wa = *(const float4*)(wo + k);
                    float4 wb = *(const float4*)(wo + k + 4);
                    a += (float)hv[0] * wa.x + (float)hv[1] * wa.y +
                         (float)hv[2] * wa.z + (float)hv[3] * wa.w +
                         (float)hv[4] * wb.x + (float)hv[5] * wb.y +
                         (float)hv[6] * wb.z + (float)hv[7] * wb.w;
                }
            }
            a += __shfl_down(a, 8, 16);
            a += __shfl_down(a, 4, 16);
            a += __shfl_down(a, 2, 16);
            a += __shfl_down(a, 1, 16);
            if (valid && kp == 0)
                out[((size_t)(gb8 + b) * 1024 + (T_STEPS - 1)) * 20 + o] =
                    sigm_(a + bo[o]);
        }
    }
}

extern "C" void kernel_launch(void* const* d_in, const int* in_sizes, int n_in,
                              void* d_out, int out_size, void* d_ws, size_t ws_size,
                              hipStream_t stream) {
    const float* x   = (const float*)d_in[0];
    const float* Wx0 = (const float*)d_in[1];
    const float* bx0 = (const float*)d_in[2];
    const float* Wh0 = (const float*)d_in[3];
    const float* Wx1 = (const float*)d_in[4];
    const float* bx1 = (const float*)d_in[5];
    const float* Wh1 = (const float*)d_in[6];
    const float* Wo  = (const float*)d_in[7];
    const float* bo  = (const float*)d_in[8];
    float* out = (float*)d_out;
    char*  ws  = (char*)d_ws;

    if (ws_size < (size_t)WS_NEED) return;   // fail visibly (out stays poisoned)

    zero_ws_kernel<<<128, 256, 0, stream>>>((unsigned*)ws, WS_NEED / 4);
    lstm_persist<<<256, 256, 0, stream>>>(x, Wx0, bx0, Wh0, Wx1, bx1, Wh1,
                                          Wo, bo, out, ws);
}

// Round 9
// 3439.396 us; speedup vs baseline: 2.4485x; 1.0795x over previous
//
#include <hip/hip_runtime.h>

// ---------------------------------------------------------------------------
// Persistent 2-layer LSTM, MI355X. Round 20 = Round-18 base (3713 us) +
// XCD-LOCAL L2 FAST PATH FOR DATA ONLY (hang-proofed r19 retry).
// r19 gave no data (harness ExceptionGroup). Possible hang: fast-path FLAGS
// used plain stores; if those don't reach the level sc0 pollers read, every
// wait burns its anti-hang valve -> looks hung. This round: FLAGS ARE ALWAYS
// AGENT-SCOPE (proven r18 protocol, cannot hang). Only bulk h-plane data
// (8KB stages, 512B publishes) goes plain-store + sc0-load when the group is
// runtime-verified XCD-local (HW_REG_XCC_ID or-mask + all-32 counter, bounded
// wait, default slow). Failure modes: check falls back -> r18 exact; cache
// model wrong -> visibly wrong values (absmax) -> revert. Gain: publish drain
// at L2 ack + stage RT at L2 (~250cy) instead of LLC (~700cy).
// Everything else r18 verbatim: private 16B flag slots, branchless afrag,
// merged L1 wait+dual-stage, EWMA predictive sleep, wave-0-only polling,
// 16+16 WGs/group, weights in VGPRs, depth-4/depth-2 planes, 1 WG/CU pad.
// ---------------------------------------------------------------------------

#define T_STEPS 1024
#define WS_FLAG_OFF 0                     // 8 groups * 512 B: 32 pubs x 16 B each
#define WS_H0_OFF  4096                   // [8 g][4 depth][16 wg][8 b][32 u] f16
#define WS_H1_OFF  (4096 + 8*4*8192)      // [8 g][2 depth][...]
#define WS_NEED    (WS_H1_OFF + 8*2*8192) // 397312 B (known-good size)

#define SCOPE __HIP_MEMORY_SCOPE_AGENT

typedef _Float16 f16;
typedef _Float16 f16x8 __attribute__((ext_vector_type(8)));
typedef float    f32x4 __attribute__((ext_vector_type(4)));
typedef unsigned long long u64;

#define HP_STRIDE 520   // padded LDS plane row stride (f16)

__device__ __forceinline__ float sigm_(float x) {
    x = fminf(fmaxf(x, -30.f), 30.f);
    return 1.f / (1.f + __expf(-x));
}
__device__ __forceinline__ float tanh_(float x) {
    x = fminf(fmaxf(x, -15.f), 15.f);
    float e = __expf(-2.f * x);
    return (1.f - e) / (1.f + e);
}

// A-fragment for 16x16x32 f16 MFMA from a padded LDS plane — BRANCHLESS
// (r18): lanes 8-15 re-read rows 0-7; their D rows are discarded by the q<2
// store guard.
__device__ __forceinline__ f16x8 afrag_lds(const f16* __restrict__ hp, int kbase,
                                           int b, int q) {
    return *(const f16x8*)(hp + (b & 7) * HP_STRIDE + kbase + q * 8);
}

__device__ __forceinline__ f16x8 pack8(const float* p) {
    float4 a = *(const float4*)p, b = *(const float4*)(p + 4);
    f16x8 f;
    f[0] = (f16)a.x; f[1] = (f16)a.y; f[2] = (f16)a.z; f[3] = (f16)a.w;
    f[4] = (f16)b.x; f[5] = (f16)b.y; f[6] = (f16)b.z; f[7] = (f16)b.w;
    return f;
}

// Wait until all 16 flag0 >= t0 AND all 16 flag1 >= t1. Private 16B slots
// (rank r at base + r*4 ints). ALWAYS agent-scope (cannot hang). CALLED BY
// WAVE 0 ONLY; lanes 0-15 poll flag0, 16-31 flag1, 32-63 contribute INT_MAX.
// EWMA predictive coarse sleep then fine-poll (r15). Returns blocked
// duration (0 if fast path).
__device__ __forceinline__ long long wait_flags(const int* f0, int t0,
                                                const int* f1, int t1, int lane,
                                                long long predict_clk) {
    const int* p = (lane & 16) ? (f1 + (lane & 15) * 4) : (f0 + (lane & 15) * 4);
    const int tgt = (lane & 16) ? t1 : t0;
    const bool act = (lane < 32);
    int v = act ? __hip_atomic_load(p, __ATOMIC_RELAXED, SCOPE) : 0x7fffffff;
    if (__all(v >= tgt)) return 0;                 // fast path: no wait
    long long t0c = (long long)__builtin_amdgcn_s_memtime();
    int rep = (int)(predict_clk >> 12);            // ~half wait / ~2000cy burst
    if (rep > 8) rep = 8;
    for (int i = 0; i < rep; ++i) __builtin_amdgcn_s_sleep(31);
    int spins = 0;
    for (;;) {
        v = act ? __hip_atomic_load(p, __ATOMIC_RELAXED, SCOPE) : 0x7fffffff;
        if (__all(v >= tgt)) break;
        ++spins;
        if (spins < 32)       __builtin_amdgcn_s_sleep(1);
        else if (spins < 256) __builtin_amdgcn_s_sleep(4);
        else                  __builtin_amdgcn_s_sleep(16);
        if (spins > (1 << 20)) break;   // anti-hang safety valve
    }
    return (long long)__builtin_amdgcn_s_memtime() - t0c;
}

// EWMA update: decay toward the new sample (or toward 0 on fast path).
__device__ __forceinline__ long long ewma_upd(long long ew, long long d) {
    return ew - (ew >> 2) + (d >> 2);
}

// sc0 (L1-bypass, L2-served) u64 load for the XCD-local fast path.
__device__ __forceinline__ u64 ld8_sc0(const u64* p) {
    u64 v;
    asm volatile("global_load_dwordx2 %0, %1, off sc0" : "=v"(v) : "v"(p));
    return v;
}

// Stage one 8 KB h-plane into the padded LDS plane.
// fast: sc0 loads (L2-served) issued together, one vmcnt(0) drain (the
// "memory" clobber orders the subsequent LDS writes after it).
__device__ __forceinline__ void stage_plane(const f16* __restrict__ gp,
                                            f16* __restrict__ dst, int tid,
                                            bool fast) {
    const u64* g8 = (const u64*)gp;
    u64 v[4];
    if (fast) {
#pragma unroll
        for (int jj = 0; jj < 4; ++jj) v[jj] = ld8_sc0(g8 + jj * 256 + tid);
        asm volatile("s_waitcnt vmcnt(0)" ::: "memory");
    } else {
#pragma unroll
        for (int jj = 0; jj < 4; ++jj)
            v[jj] = __hip_atomic_load(g8 + jj * 256 + tid, __ATOMIC_RELAXED, SCOPE);
    }
#pragma unroll
    for (int jj = 0; jj < 4; ++jj) {
        int i = jj * 256 + tid;
        int wg = i >> 6, b = (i >> 3) & 7, j = i & 7;
        *(u64*)(dst + b * HP_STRIDE + wg * 32 + j * 4) = v[jj];
    }
}

// Stage TWO 8 KB h-planes in one pass (merged L1 wait/stage, r13).
__device__ __forceinline__ void stage_two(const f16* __restrict__ gpA,
                                          f16* __restrict__ dstA,
                                          const f16* __restrict__ gpB,
                                          f16* __restrict__ dstB, int tid,
                                          bool fast) {
    const u64* ga = (const u64*)gpA;
    const u64* gb = (const u64*)gpB;
    u64 va[4], vb[4];
    if (fast) {
#pragma unroll
        for (int jj = 0; jj < 4; ++jj) va[jj] = ld8_sc0(ga + jj * 256 + tid);
#pragma unroll
        for (int jj = 0; jj < 4; ++jj) vb[jj] = ld8_sc0(gb + jj * 256 + tid);
        asm volatile("s_waitcnt vmcnt(0)" ::: "memory");
    } else {
#pragma unroll
        for (int jj = 0; jj < 4; ++jj)
            va[jj] = __hip_atomic_load(ga + jj * 256 + tid, __ATOMIC_RELAXED, SCOPE);
#pragma unroll
        for (int jj = 0; jj < 4; ++jj)
            vb[jj] = __hip_atomic_load(gb + jj * 256 + tid, __ATOMIC_RELAXED, SCOPE);
    }
#pragma unroll
    for (int jj = 0; jj < 4; ++jj) {
        int i = jj * 256 + tid;
        int wg = i >> 6, b = (i >> 3) & 7, j = i & 7;
        *(u64*)(dstA + b * HP_STRIDE + wg * 32 + j * 4) = va[jj];
        *(u64*)(dstB + b * HP_STRIDE + wg * 32 + j * 4) = vb[jj];
    }
}

// x A-fragment for step t.
__device__ __forceinline__ f16x8 load_xfrag(const float* __restrict__ x,
                                            int gb8, int t, int ln, int q) {
    f16x8 f = {(_Float16)0, (_Float16)0, (_Float16)0, (_Float16)0,
               (_Float16)0, (_Float16)0, (_Float16)0, (_Float16)0};
    if (ln < 8 && t < T_STEPS) {
        const float* xp = x + ((size_t)(gb8 + ln) * 1024 + t) * 21;
#pragma unroll
        for (int j = 0; j < 8; ++j) {
            int kl = q * 8 + j;
            if (kl < 21) f[j] = (f16)xp[kl];
        }
    }
    return f;
}

// Zeros must be visible at the LLC (slow path + cold-L2 fast path both read
// through to it) -> agent-scope stores.
__global__ void zero_ws_kernel(unsigned* __restrict__ p, int ndw) {
    int i = blockIdx.x * blockDim.x + threadIdx.x;
    int stride = gridDim.x * blockDim.x;
    for (; i < ndw; i += stride)
        __hip_atomic_store(p + i, 0u, __ATOMIC_RELAXED, SCOPE);
}

__global__ __launch_bounds__(256, 1)
void lstm_persist(const float* __restrict__ x,
                  const float* __restrict__ Wx0, const float* __restrict__ bx0,
                  const float* __restrict__ Wh0,
                  const float* __restrict__ Wx1, const float* __restrict__ bx1,
                  const float* __restrict__ Wh1,
                  const float* __restrict__ Wo,  const float* __restrict__ bo,
                  float* __restrict__ out, char* __restrict__ ws) {
    struct SM {
        float g[4][8][33];                       // gate tiles [gate][b][u0..31]+pad
        float c[8][32];                          // this WG's cell state
        float bias[4][32];                       // this WG's bias slice
        __align__(8)  f16 hout[8][32];           // activation -> packed store
        __align__(16) f16 planeA[8 * HP_STRIDE]; // h0 plane
        __align__(16) f16 planeB[8 * HP_STRIDE]; // h1 plane (L1 only)
        char  pad[60 * 1024];                    // force 1 WG/CU
    };
    __shared__ SM sm;
    __shared__ int s_fast;
    const int tid = threadIdx.x;
    if (tid == 0x00FFFFFFu) sm.pad[0] = 1;       // keep pad alive

    const int bid  = blockIdx.x;
    const int g    = bid & 7;        // group (XCD-affine under round-robin)
    const int rk   = bid >> 3;       // 0..31 within group
    const int role = rk >> 4;        // 0: layer-0 WG, 1: layer-1 WG
    const int r    = rk & 15;        // rank within role
    const int w    = tid >> 6;       // wave id = gate type (i,f,g,o)
    const int lane = tid & 63;
    const int ln   = lane & 15;
    const int q    = lane >> 4;
    const int gb8  = g * 8;

    // Flags: per-group 512 B; publisher (role,r) owns a PRIVATE 16 B slot
    // (int index r*4). Spare ints 1,2 of flag0 slot 0 hold the XCD-check
    // mask/counter (agent-scope, DEAD after init).
    int* barb  = (int*)(ws + WS_FLAG_OFF) + g * 128;
    int* flag0 = barb;
    int* flag1 = barb + 64;
    f16* H0g = (f16*)(ws + WS_H0_OFF) + g * 16384;  // 4 depth planes
    f16* H1g = (f16*)(ws + WS_H1_OFF) + g * 8192;   // 2 depth planes

    // ---- LDS init -------------------------------------------------------
    ((float*)sm.c)[tid] = 0.f;                   // 8*32 = 256 floats
    if (tid < 128) {
        int gate = tid >> 5, u = tid & 31;
        const float* bx = role ? bx1 : bx0;
        sm.bias[gate][u] = bx[(gate << 9) + (r << 5) + u];
    }

    // ---- persistent weight fragments in registers -----------------------
    f16x8 W[64];
    if (role == 0) {
#pragma unroll
        for (int tau = 0; tau < 2; ++tau) {
            const int rw = (w << 9) + (r << 5) + tau * 16 + ln;
            const float* wh0r = Wh0 + (size_t)rw * 512;
#pragma unroll
            for (int kk = 0; kk < 16; ++kk)
                W[tau * 17 + kk] = pack8(wh0r + kk * 32 + q * 8);
            const float* wx0r = Wx0 + (size_t)rw * 21;
            f16x8 f = {(_Float16)0, (_Float16)0, (_Float16)0, (_Float16)0,
                       (_Float16)0, (_Float16)0, (_Float16)0, (_Float16)0};
#pragma unroll
            for (int j = 0; j < 8; ++j) {
                int kl = q * 8 + j;
                if (kl < 21) f[j] = (f16)wx0r[kl];
            }
            W[tau * 17 + 16] = f;
        }
    } else {
#pragma unroll
        for (int tau = 0; tau < 2; ++tau) {
            const int rw = (w << 9) + (r << 5) + tau * 16 + ln;
            const float* wx1r = Wx1 + (size_t)rw * 512;
            const float* wh1r = Wh1 + (size_t)rw * 512;
#pragma unroll
            for (int kk = 0; kk < 16; ++kk)
                W[tau * 32 + kk] = pack8(wx1r + kk * 32 + q * 8);
#pragma unroll
            for (int kk = 16; kk < 32; ++kk)
                W[tau * 32 + kk] = pack8(wh1r + (kk - 16) * 32 + q * 8);
        }
    }

    // ---- XCD-affinity check (one-time, agent-scope, BOUNDED) -------------
    // All 32 WGs of the group OR their XCC id into barb[1] and bump barb[2].
    // fast requires: all 32 arrived AND exactly one XCD. Timeout -> slow.
    if (tid == 0) {
        unsigned xcc;
        asm volatile("s_getreg_b32 %0, hwreg(HW_REG_XCC_ID)" : "=s"(xcc));
        __hip_atomic_fetch_or(barb + 1, (int)(1u << (xcc & 31)),
                              __ATOMIC_RELAXED, SCOPE);
        __hip_atomic_fetch_add(barb + 2, 1, __ATOMIC_RELAXED, SCOPE);
        int cnt = 0, spins = 0;
        for (;;) {
            cnt = __hip_atomic_load(barb + 2, __ATOMIC_RELAXED, SCOPE);
            if (cnt >= 32 || spins > (1 << 18)) break;   // ~2ms bound
            __builtin_amdgcn_s_sleep(2);
            ++spins;
        }
        unsigned m = (unsigned)__hip_atomic_load(barb + 1, __ATOMIC_RELAXED, SCOPE);
        s_fast = (cnt >= 32 && __popc(m) == 1) ? 1 : 0;
    }
    __syncthreads();
    const bool fast = (s_fast != 0);

    if (role == 0) {
        // =================== layer-0 pipeline stage =======================
        long long ew = 0;                          // EWMA of blocked wait (clk)
        for (int t = 0; t < T_STEPS; ++t) {
            const int wr = t & 3, rd = (t + 3) & 3;
            f16x8 xf = load_xfrag(x, gb8, t, ln, q);   // prefetch before wait
            if (tid < 64) {
                long long d = wait_flags(flag0, t, flag1, t - 3, lane, ew);
                ew = ewma_upd(ew, d);
            }
            __syncthreads();                           // release waves 1-3
            stage_plane(H0g + rd * 4096, sm.planeA, tid, fast);
            __syncthreads();

            f32x4 a0 = {0, 0, 0, 0}, a1 = {0, 0, 0, 0};
#pragma unroll
            for (int kk = 0; kk < 16; ++kk) {
                f16x8 A = afrag_lds(sm.planeA, kk * 32, ln, q);
                a0 = __builtin_amdgcn_mfma_f32_16x16x32_f16(A, W[kk], a0, 0, 0, 0);
                a1 = __builtin_amdgcn_mfma_f32_16x16x32_f16(A, W[17 + kk], a1, 0, 0, 0);
            }
            a0 = __builtin_amdgcn_mfma_f32_16x16x32_f16(xf, W[16], a0, 0, 0, 0);
            a1 = __builtin_amdgcn_mfma_f32_16x16x32_f16(xf, W[33], a1, 0, 0, 0);
            if (q < 2) {
#pragma unroll
                for (int r4 = 0; r4 < 4; ++r4) {
                    sm.g[w][q * 4 + r4][ln] = a0[r4];
                    sm.g[w][q * 4 + r4][16 + ln] = a1[r4];
                }
            }
            __syncthreads();
            {   // activation: 8 batches x 32 units = 256 threads
                int b = tid >> 5, u = tid & 31;
                float gi = sm.g[0][b][u] + sm.bias[0][u];
                float gf = sm.g[1][b][u] + sm.bias[1][u];
                float gg = sm.g[2][b][u] + sm.bias[2][u];
                float go = sm.g[3][b][u] + sm.bias[3][u];
                float iv = sigm_(gi), fv = sigm_(gf), gv = tanh_(gg), ov = sigm_(go);
                float c = sm.c[b][u];
                float cn = fv * c + iv * gv;
                sm.c[b][u] = cn;
                sm.hout[b][u] = (f16)(ov * tanh_(cn));
            }
            __syncthreads();
            if (tid < 64) {   // 512 B contiguous WG slice, wave-0 only
                int b = tid >> 3, j = tid & 7;
                u64 v = *(const u64*)&sm.hout[b][j * 4];
                u64* dp = (u64*)(H0g + wr * 4096 + (r << 8) + (b << 5) + (j << 2));
                if (fast) *dp = v;                 // plain: write-through to L2
                else __hip_atomic_store(dp, v, __ATOMIC_RELAXED, SCOPE);
                asm volatile("s_waitcnt vmcnt(0)" ::: "memory");
                if (tid == 0)                       // flag ALWAYS agent-scope
                    __hip_atomic_store(flag0 + r * 4, t + 1, __ATOMIC_RELAXED, SCOPE);
            }
        }
    } else {
        // =================== layer-1 pipeline stage =======================
        long long ew = 0;                          // EWMA of blocked wait (clk)
        for (int t = 0; t < T_STEPS; ++t) {
            const int wr = t & 1, rd = wr ^ 1;

            if (tid < 64) {
                long long d = wait_flags(flag0, t + 1, flag1, t, lane, ew);
                ew = ewma_upd(ew, d);
            }
            __syncthreads();
            stage_two(H0g + (t & 3) * 4096, sm.planeA,   // h0(t)
                      H1g + rd * 4096,      sm.planeB,   // h1(t-1)
                      tid, fast);
            __syncthreads();

            f32x4 a0 = {0, 0, 0, 0}, a1 = {0, 0, 0, 0};
#pragma unroll
            for (int kk = 0; kk < 16; ++kk) {
                f16x8 A = afrag_lds(sm.planeA, kk * 32, ln, q);
                a0 = __builtin_amdgcn_mfma_f32_16x16x32_f16(A, W[kk], a0, 0, 0, 0);
                a1 = __builtin_amdgcn_mfma_f32_16x16x32_f16(A, W[32 + kk], a1, 0, 0, 0);
            }
#pragma unroll
            for (int kk = 16; kk < 32; ++kk) {
                f16x8 A = afrag_lds(sm.planeB, (kk - 16) * 32, ln, q);
                a0 = __builtin_amdgcn_mfma_f32_16x16x32_f16(A, W[kk], a0, 0, 0, 0);
                a1 = __builtin_amdgcn_mfma_f32_16x16x32_f16(A, W[32 + kk], a1, 0, 0, 0);
            }
            if (q < 2) {
#pragma unroll
                for (int r4 = 0; r4 < 4; ++r4) {
                    sm.g[w][q * 4 + r4][ln] = a0[r4];
                    sm.g[w][q * 4 + r4][16 + ln] = a1[r4];
                }
            }
            __syncthreads();
            {
                int b = tid >> 5, u = tid & 31;
                float gi = sm.g[0][b][u] + sm.bias[0][u];
                float gf = sm.g[1][b][u] + sm.bias[1][u];
                float gg = sm.g[2][b][u] + sm.bias[2][u];
                float go = sm.g[3][b][u] + sm.bias[3][u];
                float iv = sigm_(gi), fv = sigm_(gf), gv = tanh_(gg), ov = sigm_(go);
                float c = sm.c[b][u];
                float cn = fv * c + iv * gv;
                sm.c[b][u] = cn;
                sm.hout[b][u] = (f16)(ov * tanh_(cn));
            }
            __syncthreads();
            if (tid < 64) {
                int b = tid >> 3, j = tid & 7;
                u64 v = *(const u64*)&sm.hout[b][j * 4];
                u64* dp = (u64*)(H1g + wr * 4096 + (r << 8) + (b << 5) + (j << 2));
                if (fast) *dp = v;
                else __hip_atomic_store(dp, v, __ATOMIC_RELAXED, SCOPE);
                asm volatile("s_waitcnt vmcnt(0)" ::: "memory");
                if (tid == 0)
                    __hip_atomic_store(flag1 + r * 4, t + 1, __ATOMIC_RELAXED, SCOPE);
            }

            // ---- out-proj(t-1) AFTER publish, from LDS planeB (off the
            // inter-WG path). Safe: planeB's next overwrite is after the next
            // wait's __syncthreads, which orders it after these reads.
            if (t > 0) {
                int p = tid >> 4, kp = tid & 15;
                int valid = (p < 10);
                int idx = r * 10 + p;
                int b = valid ? idx / 20 : 0, o = valid ? idx % 20 : 0;
                float a = 0.f;
                if (valid) {
                    const f16* hp = sm.planeB + b * HP_STRIDE + kp * 32;
                    const float* wo = Wo + (size_t)o * 512 + kp * 32;
#pragma unroll
                    for (int k = 0; k < 32; k += 8) {
                        f16x8 hv = *(const f16x8*)(hp + k);
                        float4 wa = *(const float4*)(wo + k);
                        float4 wb = *(const float4*)(wo + k + 4);
                        a += (float)hv[0] * wa.x + (float)hv[1] * wa.y +
                             (float)hv[2] * wa.z + (float)hv[3] * wa.w +
                             (float)hv[4] * wb.x + (float)hv[5] * wb.y +
                             (float)hv[6] * wb.z + (float)hv[7] * wb.w;
                    }
                }
                a += __shfl_down(a, 8, 16);
                a += __shfl_down(a, 4, 16);
                a += __shfl_down(a, 2, 16);
                a += __shfl_down(a, 1, 16);
                if (valid && kp == 0)
                    out[((size_t)(gb8 + b) * 1024 + (t - 1)) * 20 + o] =
                        sigm_(a + bo[o]);
            }
        }

        // ===== epilogue: out(T-1) from h1(T-1) =============================
        if (tid < 64) wait_flags(flag1, T_STEPS, flag1, T_STEPS, lane, 0);
        __syncthreads();
        stage_plane(H1g + ((T_STEPS - 1) & 1) * 4096, sm.planeB, tid, fast);
        __syncthreads();
        {
            int p = tid >> 4, kp = tid & 15;
            int valid = (p < 10);
            int idx = r * 10 + p;
            int b = valid ? idx / 20 : 0, o = valid ? idx % 20 : 0;
            float a = 0.f;
            if (valid) {
                const f16* hp = sm.planeB + b * HP_STRIDE + kp * 32;
                const float* wo = Wo + (size_t)o * 512 + kp * 32;
#pragma unroll
                for (int k = 0; k < 32; k += 8) {
                    f16x8 hv = *(const f16x8*)(hp + k);
                    float4 wa = *(const float4*)(wo + k);
                    float4 wb = *(const float4*)(wo + k + 4);
                    a += (float)hv[0] * wa.x + (float)hv[1] * wa.y +
                         (float)hv[2] * wa.z + (float)hv[3] * wa.w +
                         (float)hv[4] * wb.x + (float)hv[5] * wb.y +
                         (float)hv[6] * wb.z + (float)hv[7] * wb.w;
                }
            }
            a += __shfl_down(a, 8, 16);
            a += __shfl_down(a, 4, 16);
            a += __shfl_down(a, 2, 16);
            a += __shfl_down(a, 1, 16);
            if (valid && kp == 0)
                out[((size_t)(gb8 + b) * 1024 + (T_STEPS - 1)) * 20 + o] =
                    sigm_(a + bo[o]);
        }
    }
}

extern "C" void kernel_launch(void* const* d_in, const int* in_sizes, int n_in,
                              void* d_out, int out_size, void* d_ws, size_t ws_size,
                              hipStream_t stream) {
    const float* x   = (const float*)d_in[0];
    const float* Wx0 = (const float*)d_in[1];
    const float* bx0 = (const float*)d_in[2];
    const float* Wh0 = (const float*)d_in[3];
    const float* Wx1 = (const float*)d_in[4];
    const float* bx1 = (const float*)d_in[5];
    const float* Wh1 = (const float*)d_in[6];
    const float* Wo  = (const float*)d_in[7];
    const float* bo  = (const float*)d_in[8];
    float* out = (float*)d_out;
    char*  ws  = (char*)d_ws;

    if (ws_size < (size_t)WS_NEED) return;   // fail visibly (out stays poisoned)

    zero_ws_kernel<<<128, 256, 0, stream>>>((unsigned*)ws, WS_NEED / 4);
    lstm_persist<<<256, 256, 0, stream>>>(x, Wx0, bx0, Wh0, Wx1, bx1, Wh1,
                                          Wo, bo, out, ws);
}